// Round 1
// baseline (190.134 us; speedup 1.0000x reference)
//
#include <hip/hip_runtime.h>
#include <hip/hip_bf16.h>

#define TEMP_INV 2.0f   // 1 / 0.5
#define EPS 1e-8f
#define NROWS 4096
#define DDIM 256

typedef __attribute__((ext_vector_type(8))) short short8;
typedef __attribute__((ext_vector_type(4))) float f32x4;

// ---------------------------------------------------------------------------
// Kernel 1: row L2-normalize fp32 -> bf16, and zero the row-sum array S.
// grid = 2N blocks x 256 threads (one thread per element, D=256).
__global__ void normalize_kernel(const float* __restrict__ a,
                                 const float* __restrict__ b,
                                 __hip_bfloat16* __restrict__ en,
                                 float* __restrict__ S, int N) {
    const int row = blockIdx.x;                 // 0 .. 2N-1
    const int t = threadIdx.x;                  // 0 .. 255
    const float* src = (row < N) ? (a + (size_t)row * DDIM)
                                 : (b + (size_t)(row - N) * DDIM);
    float x = src[t];
    float ss = x * x;
    #pragma unroll
    for (int off = 32; off > 0; off >>= 1) ss += __shfl_xor(ss, off);
    __shared__ float wsum[4];
    const int wave = t >> 6, lane = t & 63;
    if (lane == 0) wsum[wave] = ss;
    __syncthreads();
    const float tot = wsum[0] + wsum[1] + wsum[2] + wsum[3];
    const float inv = 1.0f / fmaxf(sqrtf(tot), EPS);
    en[(size_t)row * DDIM + t] = __float2bfloat16(x * inv);
    if (t == 0 && row < N) S[row] = 0.0f;
}

// ---------------------------------------------------------------------------
// Kernel 2: pos[i] = <en[i], en[N+i]> / T.  grid = N blocks x 64 threads.
__global__ void pos_kernel(const __hip_bfloat16* __restrict__ en,
                           float* __restrict__ pos, int N) {
    const int i = blockIdx.x;
    const int lane = threadIdx.x;               // 0..63, 4 elems each
    const __hip_bfloat16* pa = en + (size_t)i * DDIM + lane * 4;
    const __hip_bfloat16* pb = en + (size_t)(N + i) * DDIM + lane * 4;
    float acc = 0.0f;
    #pragma unroll
    for (int r = 0; r < 4; ++r)
        acc += __bfloat162float(pa[r]) * __bfloat162float(pb[r]);
    #pragma unroll
    for (int off = 32; off > 0; off >>= 1) acc += __shfl_xor(acc, off);
    if (lane == 0) pos[i] = acc * TEMP_INV;
}

// ---------------------------------------------------------------------------
// Kernel 3: masked exp row sums via MFMA.
// grid = (M/64, JSLICES), block = 256 (4 waves). Wave w owns rows
// i0 = bx*64 + w*16 .. +15, sweeps its j-slice in 16-col chunks.
// A-frags (16 rows x K=256) live in 32 VGPRs for the whole kernel.
// MFMA 16x16x32 bf16 verified layouts:
//   A/B operand: elem j of lane l = En[rowbase + (l&15)][kstep*32 + (l>>4)*8 + j]
//   C/D:         reg r of lane l  = C[(l>>4)*4 + r][l&15]
__global__ __launch_bounds__(256) void simsum_kernel(
        const __hip_bfloat16* __restrict__ en_h,
        float* __restrict__ S, int N, int jslice) {
    const short* en = (const short*)en_h;
    const int tid = threadIdx.x;
    const int wave = tid >> 6, lane = tid & 63;
    const int lrow = lane & 15, quad = lane >> 4;
    const int i0 = blockIdx.x * 64 + wave * 16;

    // Load A fragments once (row i0+lrow, all K)
    short8 afrag[8];
    #pragma unroll
    for (int ks = 0; ks < 8; ++ks) {
        const int k = ks * 32 + quad * 8;
        afrag[ks] = *reinterpret_cast<const short8*>(
            en + (size_t)(i0 + lrow) * DDIM + k);
    }

    float rowsum[4] = {0.f, 0.f, 0.f, 0.f};
    const int j_begin = blockIdx.y * jslice;
    const int j_end = j_begin + jslice;
    for (int j0 = j_begin; j0 < j_end; j0 += 16) {
        const size_t brow = (size_t)(j0 + lrow) * DDIM;
        f32x4 acc = {0.f, 0.f, 0.f, 0.f};
        #pragma unroll
        for (int ks = 0; ks < 8; ++ks) {
            const int k = ks * 32 + quad * 8;
            short8 bfrag = *reinterpret_cast<const short8*>(en + brow + k);
            acc = __builtin_amdgcn_mfma_f32_16x16x32_bf16(afrag[ks], bfrag, acc,
                                                          0, 0, 0);
        }
        const int col_mod = (j0 + lrow) & (N - 1);   // N = 4096 (pow2)
        #pragma unroll
        for (int r = 0; r < 4; ++r) {
            const int row = i0 + quad * 4 + r;       // row < N always
            const float s = acc[r] * TEMP_INV;
            rowsum[r] += (col_mod != row) ? __expf(s) : 0.0f;
        }
    }

    // Reduce each rowsum[r] across the 16 lanes (low-4-bit group = same quad)
    #pragma unroll
    for (int r = 0; r < 4; ++r) {
        float v = rowsum[r];
        v += __shfl_xor(v, 1);
        v += __shfl_xor(v, 2);
        v += __shfl_xor(v, 4);
        v += __shfl_xor(v, 8);
        rowsum[r] = v;
    }
    if (lrow < 4) {
        atomicAdd(&S[i0 + quad * 4 + lrow], rowsum[lrow]);
    }
}

// ---------------------------------------------------------------------------
// Kernel 4: loss = -(1/N) * sum_i (pos[i] - log(S[i])). One block.
__global__ void loss_kernel(const float* __restrict__ S,
                            const float* __restrict__ pos,
                            float* __restrict__ out, int N) {
    float acc = 0.0f;
    for (int i = threadIdx.x; i < N; i += blockDim.x)
        acc += pos[i] - __logf(S[i]);
    #pragma unroll
    for (int off = 32; off > 0; off >>= 1) acc += __shfl_xor(acc, off);
    __shared__ float wsum[4];
    const int wave = threadIdx.x >> 6, lane = threadIdx.x & 63;
    if (lane == 0) wsum[wave] = acc;
    __syncthreads();
    if (threadIdx.x == 0)
        out[0] = -(wsum[0] + wsum[1] + wsum[2] + wsum[3]) / (float)N;
}

// ---------------------------------------------------------------------------
extern "C" void kernel_launch(void* const* d_in, const int* in_sizes, int n_in,
                              void* d_out, int out_size, void* d_ws, size_t ws_size,
                              hipStream_t stream) {
    const float* a = (const float*)d_in[0];
    const float* b = (const float*)d_in[1];
    float* out = (float*)d_out;
    const int N = NROWS;

    char* ws = (char*)d_ws;
    __hip_bfloat16* en = (__hip_bfloat16*)ws;                    // 2N*D*2 = 4 MB
    float* S = (float*)(ws + (size_t)2 * N * DDIM * sizeof(__hip_bfloat16));
    float* pos = S + N;

    normalize_kernel<<<2 * N, 256, 0, stream>>>(a, b, en, S, N);
    pos_kernel<<<N, 64, 0, stream>>>(en, pos, N);
    // 64 row-blocks x 16 j-slices = 1024 blocks; jslice = 8192/16 = 512
    simsum_kernel<<<dim3(N / 64, 16), 256, 0, stream>>>(en, S, N, (2 * N) / 16);
    loss_kernel<<<1, 256, 0, stream>>>(S, pos, out, N);
}

// Round 2
// 96.669 us; speedup vs baseline: 1.9669x; 1.9669x over previous
//
#include <hip/hip_runtime.h>
#include <hip/hip_bf16.h>

#define NROWS 4096
#define DDIM  256
#define EPS   1e-8f
// Store normalized rows scaled by sqrt(2*log2(e)) so that the MFMA dot is
// directly the exp2 argument: exp2(s^2 * <e_i,e_j>) = exp(<e_i,e_j>/T), T=0.5.
#define SCALE 1.69864944f     // sqrt(2.88539008)
#define LN2   0.69314718056f

#define NJ    32              // j-slices  -> grid.y
#define JS    256             // cols per slice (8192/NJ)
#define BT    32              // cols staged in LDS per chunk
#define LSTRIDE 264           // LDS row stride in shorts (256 + 8 pad)

typedef __attribute__((ext_vector_type(8))) short short8;
typedef __attribute__((ext_vector_type(4))) float f32x4;

#if __has_builtin(__builtin_amdgcn_exp2f)
#define EXP2F(x) __builtin_amdgcn_exp2f(x)
#else
#define EXP2F(x) exp2f(x)
#endif

// ---------------------------------------------------------------------------
// Kernel 1: row L2-normalize fp32 -> bf16 (scaled), zero S.
// grid = 2N blocks x 256 threads.
__global__ void normalize_kernel(const float* __restrict__ a,
                                 const float* __restrict__ b,
                                 __hip_bfloat16* __restrict__ en,
                                 float* __restrict__ S, int N) {
    const int row = blockIdx.x;
    const int t = threadIdx.x;
    const float* src = (row < N) ? (a + (size_t)row * DDIM)
                                 : (b + (size_t)(row - N) * DDIM);
    float x = src[t];
    float ss = x * x;
    #pragma unroll
    for (int off = 32; off > 0; off >>= 1) ss += __shfl_xor(ss, off);
    __shared__ float wsum[4];
    const int wave = t >> 6, lane = t & 63;
    if (lane == 0) wsum[wave] = ss;
    __syncthreads();
    const float tot = wsum[0] + wsum[1] + wsum[2] + wsum[3];
    const float inv = SCALE / fmaxf(sqrtf(tot), EPS);
    en[(size_t)row * DDIM + t] = __float2bfloat16(x * inv);
    if (t == 0 && row < N) S[row] = 0.0f;
}

// ---------------------------------------------------------------------------
// Kernel 2: masked exp row-sums via MFMA, B staged in LDS shared by 4 waves,
// 64 A-rows register-resident per wave (4 MFMAs per B-frag LDS read).
// Also harvests positive_sim from the masked diagonal cell (col = N + row).
// grid = (16 i-blocks of 256 rows, NJ j-slices), block = 256.
// MFMA 16x16x32 bf16 verified layouts:
//   A/B operand: elem j of lane l = M[base + (l&15)][ks*32 + (l>>4)*8 + j]
//   C/D:         reg r of lane l  = C[(l>>4)*4 + r][l&15]
__global__ __launch_bounds__(256) void simsum_kernel(
        const short* __restrict__ en,
        float* __restrict__ S,
        float* __restrict__ pos) {
    __shared__ short bt[BT * LSTRIDE];
    const int tid = threadIdx.x;
    const int wave = tid >> 6, lane = tid & 63;
    const int lrow = lane & 15, quad = lane >> 4;
    const int i0 = blockIdx.x * 256 + wave * 64;

    // A fragments: 4 row-tiles x full K=256 -> 128 VGPRs, loaded once.
    short8 afrag[4][8];
    #pragma unroll
    for (int t = 0; t < 4; ++t) {
        #pragma unroll
        for (int ks = 0; ks < 8; ++ks) {
            afrag[t][ks] = *reinterpret_cast<const short8*>(
                en + (size_t)(i0 + t * 16 + lrow) * DDIM + ks * 32 + quad * 8);
        }
    }

    float rowsum[4][4];
    #pragma unroll
    for (int t = 0; t < 4; ++t)
        #pragma unroll
        for (int r = 0; r < 4; ++r) rowsum[t][r] = 0.0f;

    const int jb = blockIdx.y * JS;
    for (int jc = jb; jc < jb + JS; jc += BT) {
        __syncthreads();
        // Stage BT=32 B-rows (16 KB) into padded LDS: 4 iters x 16B/thread,
        // global side is a single contiguous 16 KB range -> fully coalesced.
        const short* src = en + (size_t)jc * DDIM;
        #pragma unroll
        for (int it = 0; it < 4; ++it) {
            const int off = it * 2048 + tid * 8;     // offset in shorts
            short8 v = *reinterpret_cast<const short8*>(src + off);
            *reinterpret_cast<short8*>(
                &bt[(off >> 8) * LSTRIDE + (off & 255)]) = v;
        }
        __syncthreads();

        #pragma unroll
        for (int c = 0; c < 2; ++c) {
            f32x4 acc[4];
            #pragma unroll
            for (int t = 0; t < 4; ++t) acc[t] = f32x4{0.f, 0.f, 0.f, 0.f};
            #pragma unroll
            for (int ks = 0; ks < 8; ++ks) {
                short8 bfrag = *reinterpret_cast<const short8*>(
                    &bt[(c * 16 + lrow) * LSTRIDE + ks * 32 + quad * 8]);
                #pragma unroll
                for (int t = 0; t < 4; ++t) {
                    acc[t] = __builtin_amdgcn_mfma_f32_16x16x32_bf16(
                        afrag[t][ks], bfrag, acc[t], 0, 0, 0);
                }
            }
            const int col = jc + c * 16 + lrow;      // global column
            const int cm = col & (NROWS - 1);        // col % N (N pow2)
            #pragma unroll
            for (int t = 0; t < 4; ++t) {
                const int rbase = i0 + t * 16 + quad * 4;
                #pragma unroll
                for (int r = 0; r < 4; ++r) {
                    const float d = acc[t][r];       // = (sim/T)*log2(e)
                    const int row = rbase + r;
                    rowsum[t][r] += (cm != row) ? EXP2F(d) : 0.0f;
                    if (cm == row && col >= NROWS)   // this cell IS positive_sim
                        pos[row] = d * LN2;
                }
            }
        }
    }

    // Reduce each rowsum over the 16 lanes sharing a quad, then one atomic.
    #pragma unroll
    for (int t = 0; t < 4; ++t) {
        #pragma unroll
        for (int r = 0; r < 4; ++r) {
            float v = rowsum[t][r];
            v += __shfl_xor(v, 1);
            v += __shfl_xor(v, 2);
            v += __shfl_xor(v, 4);
            v += __shfl_xor(v, 8);
            rowsum[t][r] = v;
        }
        if (lrow < 4) {
            const float v = (lrow == 0) ? rowsum[t][0]
                          : (lrow == 1) ? rowsum[t][1]
                          : (lrow == 2) ? rowsum[t][2]
                          :               rowsum[t][3];
            atomicAdd(&S[i0 + t * 16 + quad * 4 + lrow], v);
        }
    }
}

// ---------------------------------------------------------------------------
// Kernel 3: loss = -(1/N) * sum_i (pos[i] - log(S[i])). One block.
__global__ void loss_kernel(const float* __restrict__ S,
                            const float* __restrict__ pos,
                            float* __restrict__ out, int N) {
    float acc = 0.0f;
    for (int i = threadIdx.x; i < N; i += blockDim.x)
        acc += pos[i] - __logf(S[i]);
    #pragma unroll
    for (int off = 32; off > 0; off >>= 1) acc += __shfl_xor(acc, off);
    __shared__ float wsum[4];
    const int wave = threadIdx.x >> 6, lane = threadIdx.x & 63;
    if (lane == 0) wsum[wave] = acc;
    __syncthreads();
    if (threadIdx.x == 0)
        out[0] = -(wsum[0] + wsum[1] + wsum[2] + wsum[3]) / (float)N;
}

// ---------------------------------------------------------------------------
extern "C" void kernel_launch(void* const* d_in, const int* in_sizes, int n_in,
                              void* d_out, int out_size, void* d_ws, size_t ws_size,
                              hipStream_t stream) {
    const float* a = (const float*)d_in[0];
    const float* b = (const float*)d_in[1];
    float* out = (float*)d_out;
    const int N = NROWS;

    char* ws = (char*)d_ws;
    __hip_bfloat16* en = (__hip_bfloat16*)ws;                  // 2N*D*2 = 4 MB
    float* S = (float*)(ws + (size_t)2 * N * DDIM * sizeof(__hip_bfloat16));
    float* pos = S + N;

    normalize_kernel<<<2 * N, 256, 0, stream>>>(a, b, en, S, N);
    simsum_kernel<<<dim3(N / 256, NJ), 256, 0, stream>>>((const short*)en, S, pos);
    loss_kernel<<<1, 256, 0, stream>>>(S, pos, out, N);
}

// Round 3
// 88.485 us; speedup vs baseline: 2.1488x; 1.0925x over previous
//
#include <hip/hip_runtime.h>
#include <hip/hip_bf16.h>

#define NROWS 4096
#define DDIM  256
#define EPS   1e-8f
// Normalized rows are scaled by sqrt(2*log2(e)) so the MFMA dot product IS the
// exp2 argument: exp2(<se_i, se_j>) = exp(<e_i,e_j>/T), T = 0.5.
#define SCALE 1.69864944f
#define LN2   0.69314718056f

#define NJ 32          // j-slices (grid.y)
#define JS 256         // cols per slice
#define BT 64          // cols per staged LDS chunk
#define CH (JS / BT)   // 4 chunks per slice
// LDS fragment-ordered: [buf][cgrp(4)][ks(8)][lane(64)][8 shorts] = 32 KB/buf
#define BUFSH (4 * 8 * 64 * 8)

typedef __attribute__((ext_vector_type(8))) short short8;
typedef __attribute__((ext_vector_type(4))) float f32x4;

#if __has_builtin(__builtin_amdgcn_exp2f)
#define EXP2F(x) __builtin_amdgcn_exp2f(x)
#else
#define EXP2F(x) exp2f(x)
#endif

__device__ __forceinline__ unsigned short f2bf(float x) {
    union { __hip_bfloat16 h; unsigned short u; } c;
    c.h = __float2bfloat16(x);
    return c.u;
}

// ---------------------------------------------------------------------------
// Kernel 1: row L2-normalize fp32 -> scaled bf16; zero S.
// One wave per row: grid = 2N/4 blocks x 256 threads.
__global__ void normalize_kernel(const float* __restrict__ a,
                                 const float* __restrict__ b,
                                 unsigned short* __restrict__ en,
                                 float* __restrict__ S, int N) {
    const int wave = threadIdx.x >> 6, lane = threadIdx.x & 63;
    const int row = blockIdx.x * 4 + wave;
    const float* src = (row < N) ? (a + (size_t)row * DDIM)
                                 : (b + (size_t)(row - N) * DDIM);
    const float4 v = reinterpret_cast<const float4*>(src)[lane];
    float ss = v.x * v.x + v.y * v.y + v.z * v.z + v.w * v.w;
    #pragma unroll
    for (int off = 32; off > 0; off >>= 1) ss += __shfl_xor(ss, off);
    const float inv = SCALE / fmaxf(sqrtf(ss), EPS * SCALE);
    ushort4 o;
    o.x = f2bf(v.x * inv);
    o.y = f2bf(v.y * inv);
    o.z = f2bf(v.z * inv);
    o.w = f2bf(v.w * inv);
    *reinterpret_cast<ushort4*>(en + (size_t)row * DDIM + lane * 4) = o;
    if (lane == 0 && row < N) S[row] = 0.0f;
}

// ---------------------------------------------------------------------------
// Kernel 2: masked exp row-sums via MFMA.
// grid = (16 i-blocks of 256 rows, NJ j-slices), block = 256 (4 waves).
// Each wave holds 64 A-rows register-resident (128 VGPRs); B staged in
// double-buffered LDS via async global_load_lds (fragment order, lane*16B).
// Epilogue is mask-free exp2+add; diagonal-family terms (self + positive)
// are undone in a rare exec-masked branch, which also harvests positive_sim.
// MFMA 16x16x32 bf16 verified layouts:
//   A/B operand: elem j of lane l = M[base + (l&15)][ks*32 + (l>>4)*8 + j]
//   C/D:         reg r of lane l  = C[(l>>4)*4 + r][l&15]
__global__ __launch_bounds__(256, 2) void simsum_kernel(
        const short* __restrict__ en,
        float* __restrict__ S,
        float* __restrict__ pos) {
    __shared__ short bt[2 * BUFSH];
    const int tid = threadIdx.x;
    const int wave = tid >> 6, lane = tid & 63;
    const int lrow = lane & 15, quad = lane >> 4;
    const int i0 = blockIdx.x * 256 + wave * 64;
    const int jb = blockIdx.y * JS;

    // A fragments: 4 row-tiles x K=256, loaded once.
    short8 afrag[4][8];
    #pragma unroll
    for (int t = 0; t < 4; ++t)
        #pragma unroll
        for (int ks = 0; ks < 8; ++ks)
            afrag[t][ks] = *reinterpret_cast<const short8*>(
                en + (size_t)(i0 + t * 16 + lrow) * DDIM + ks * 32 + quad * 8);

    float rowsum[4][4];
    #pragma unroll
    for (int t = 0; t < 4; ++t)
        #pragma unroll
        for (int r = 0; r < 4; ++r) rowsum[t][r] = 0.0f;

    // Async stage of one 64-col chunk: wave w stages row-group w (16 cols),
    // all 8 k-steps. DMA writes LDS at uniform base + lane*16B, which is
    // exactly fragment order for the consuming ds_read_b128.
    auto stage = [&](int jc, int buf) {
        const short* g = en + (size_t)(jc + wave * 16 + lrow) * DDIM + quad * 8;
        short* l = bt + buf * BUFSH + wave * 4096;
        #pragma unroll
        for (int ks = 0; ks < 8; ++ks) {
            __builtin_amdgcn_global_load_lds(
                (const __attribute__((address_space(1))) void*)(g + ks * 32),
                (__attribute__((address_space(3))) void*)(l + ks * 512),
                16, 0, 0);
        }
    };

    stage(jb, 0);
    for (int c = 0; c < CH; ++c) {
        __syncthreads();                       // chunk c staged; prev readers done
        if (c + 1 < CH) stage(jb + (c + 1) * BT, (c + 1) & 1);
        const short* lb = bt + (c & 1) * BUFSH;
        #pragma unroll
        for (int cg = 0; cg < 4; ++cg) {
            f32x4 acc[4];
            #pragma unroll
            for (int t = 0; t < 4; ++t) acc[t] = f32x4{0.f, 0.f, 0.f, 0.f};
            #pragma unroll
            for (int ks = 0; ks < 8; ++ks) {
                const short8 bfrag = *reinterpret_cast<const short8*>(
                    lb + cg * 4096 + ks * 512 + lane * 8);
                #pragma unroll
                for (int t = 0; t < 4; ++t)
                    acc[t] = __builtin_amdgcn_mfma_f32_16x16x32_bf16(
                        afrag[t][ks], bfrag, acc[t], 0, 0, 0);
            }
            const int col = jb + c * BT + cg * 16 + lrow;
            const int cm = col & (NROWS - 1);
            #pragma unroll
            for (int t = 0; t < 4; ++t) {
                #pragma unroll
                for (int r = 0; r < 4; ++r)
                    rowsum[t][r] += EXP2F(acc[t][r]);
                const unsigned delta = (unsigned)(cm - (i0 + t * 16 + quad * 4));
                if (delta < 4u) {              // diagonal-family cell (rare)
                    const float d = (delta == 0) ? acc[t][0]
                                  : (delta == 1) ? acc[t][1]
                                  : (delta == 2) ? acc[t][2]
                                  :                acc[t][3];
                    const float ed = EXP2F(d);
                    #pragma unroll
                    for (int r = 0; r < 4; ++r)
                        if (r == (int)delta) rowsum[t][r] -= ed;
                    if (col >= NROWS) pos[cm] = d * LN2;  // positive_sim
                }
            }
        }
    }

    // Reduce each rowsum over the 16 lanes sharing a quad, then one atomic.
    #pragma unroll
    for (int t = 0; t < 4; ++t) {
        #pragma unroll
        for (int r = 0; r < 4; ++r) {
            float v = rowsum[t][r];
            v += __shfl_xor(v, 1);
            v += __shfl_xor(v, 2);
            v += __shfl_xor(v, 4);
            v += __shfl_xor(v, 8);
            rowsum[t][r] = v;
        }
        if (lrow < 4) {
            const float v = (lrow == 0) ? rowsum[t][0]
                          : (lrow == 1) ? rowsum[t][1]
                          : (lrow == 2) ? rowsum[t][2]
                          :               rowsum[t][3];
            atomicAdd(&S[i0 + t * 16 + quad * 4 + lrow], v);
        }
    }
}

// ---------------------------------------------------------------------------
// Kernel 3: loss = -(1/N) * sum_i (pos[i] - log(S[i])). One block x 1024.
__global__ void loss_kernel(const float* __restrict__ S,
                            const float* __restrict__ pos,
                            float* __restrict__ out, int N) {
    float acc = 0.0f;
    for (int i = threadIdx.x; i < N; i += 1024)
        acc += pos[i] - __logf(S[i]);
    #pragma unroll
    for (int off = 32; off > 0; off >>= 1) acc += __shfl_xor(acc, off);
    __shared__ float wsum[16];
    const int wave = threadIdx.x >> 6, lane = threadIdx.x & 63;
    if (lane == 0) wsum[wave] = acc;
    __syncthreads();
    if (threadIdx.x == 0) {
        float tot = 0.0f;
        #pragma unroll
        for (int w = 0; w < 16; ++w) tot += wsum[w];
        out[0] = -tot / (float)N;
    }
}

// ---------------------------------------------------------------------------
extern "C" void kernel_launch(void* const* d_in, const int* in_sizes, int n_in,
                              void* d_out, int out_size, void* d_ws, size_t ws_size,
                              hipStream_t stream) {
    const float* a = (const float*)d_in[0];
    const float* b = (const float*)d_in[1];
    float* out = (float*)d_out;
    const int N = NROWS;

    char* ws = (char*)d_ws;
    unsigned short* en = (unsigned short*)ws;                  // 2N*D*2 = 4 MB
    float* S = (float*)(ws + (size_t)2 * N * DDIM * sizeof(unsigned short));
    float* pos = S + N;

    normalize_kernel<<<(2 * N) / 4, 256, 0, stream>>>(a, b, en, S, N);
    simsum_kernel<<<dim3(N / 256, NJ), 256, 0, stream>>>((const short*)en, S, pos);
    loss_kernel<<<1, 1024, 0, stream>>>(S, pos, out, N);
}